// Round 6
// baseline (15.676 us; speedup 1.0000x reference)
//
#include <hip/hip_runtime.h>
#include <math.h>

#define BB 4
#define PP 16384
#define GG 512
#define HH 512
#define WW 512
#define GPB 32           // g's per block in kernel 2
#define BPB 16           // blocks per batch = GG/GPB
#define NTHR2 1024       // 16 waves; each wave handles 2 g's
#define CAPL 128         // LDS bucket capacity (mean 32; P(>128) ~ 1e-40)

typedef unsigned short u16;
typedef __attribute__((ext_vector_type(8))) unsigned short u16x8;

__device__ __forceinline__ float distf(float px, float py, float gx, float gy) {
#pragma clang fp contract(off)
    float dx = px - gx;
    float dy = py - gy;
    float a = dx * dx;
    float c = dy * dy;
    return sqrtf(a + c);   // matches XLA: separate mul/add/sqrt, no FMA contraction
}

// Kernel 1: each point labeled exactly once (the only random-gather pass).
// Pure u16 writes to labels[] -> no init, no atomics, no workspace counts.
__global__ void k_label(const float* __restrict__ pred, const int* __restrict__ lm,
                        u16* __restrict__ labels) {
    int t = blockIdx.x * blockDim.x + threadIdx.x;   // [0, B*P) exactly
    int b = t >> 14;                                  // t / PP
    float2 c = ((const float2*)pred)[t];
    int x = min(max((int)rintf(c.x), 0), WW - 1);     // round half-to-even = jnp.round
    int y = min(max((int)rintf(c.y), 0), HH - 1);
    labels[t] = (u16)lm[((b << 9) + y) * WW + x];     // b*HH*WW + y*WW + x
}

// Kernel 2: one block per (batch, 32-g range). Coalesced 16B scan of the
// block's u16 labels slice -> LDS index buckets -> waves resolve 2 g's each.
__global__ void __launch_bounds__(NTHR2) k_match(const float* __restrict__ pred,
                                                 const float* __restrict__ gt,
                                                 const u16* __restrict__ labels,
                                                 float* __restrict__ out) {
    __shared__ int cnt[GPB];
    __shared__ int bidx[GPB][CAPL];

    const int b     = blockIdx.x / BPB;
    const int gbase = (blockIdx.x % BPB) * GPB;
    const int tid   = threadIdx.x;

    if (tid < GPB) cnt[tid] = 0;
    __syncthreads();

    const float2* predb = (const float2*)(pred + (size_t)b * PP * 2);
    const u16*    labb  = labels + (size_t)b * PP;

    // ---- Phase A: coalesced u16x8 label scan, bucket indices for our 32 g's
    const u16x8* lab8 = (const u16x8*)labb;
    #pragma unroll
    for (int i = tid; i < PP / 8; i += NTHR2) {       // 2 iterations
        u16x8 lv = lab8[i];
        int p0 = i * 8;
        #pragma unroll
        for (int j = 0; j < 8; ++j) {
            int lg = (int)lv[j] - 1 - gbase;
            if ((unsigned)lg < GPB) {
                int s = atomicAdd(&cnt[lg], 1);       // LDS atomic, block-local
                if (s < CAPL) bidx[lg][s] = p0 + j;
            }
        }
    }
    __syncthreads();

    // ---- Phase B: wave w resolves g = gbase + w and gbase + 16 + w
    const int w    = tid >> 6;
    const int lane = tid & 63;

    for (int lw = w; lw < GPB; lw += 16) {
        const int g    = gbase + lw;
        const float gx = gt[(size_t)(b * GG + g) * 2 + 0];
        const float gy = gt[(size_t)(b * GG + g) * 2 + 1];
        const int n = cnt[lw];

        float bd = INFINITY;
        int   bi = 0x7fffffff;

        if (n == 0) {
            // empty mask: argmin over ALL points (reference fallback); ~never taken
            for (int p = lane; p < PP; p += 64) {
                float2 c = predb[p];
                float d = distf(c.x, c.y, gx, gy);
                if (d < bd || (d == bd && p < bi)) { bd = d; bi = p; }
            }
        } else if (n <= CAPL) {
            for (int e = lane; e < n; e += 64) {      // 1 iteration typically
                int p = bidx[lw][e];
                float2 c = predb[p];
                float d = distf(c.x, c.y, gx, gy);
                if (d < bd || (d == bd && p < bi)) { bd = d; bi = p; }
            }
        } else {
            // bucket overflow (~impossible): exact coalesced re-filter
            for (int p = lane; p < PP; p += 64) {
                if ((int)labb[p] == g + 1) {
                    float2 c = predb[p];
                    float d = distf(c.x, c.y, gx, gy);
                    if (d < bd || (d == bd && p < bi)) { bd = d; bi = p; }
                }
            }
        }

        // wave butterfly reduce: (min d, then min original index) — order-invariant
        for (int off = 32; off > 0; off >>= 1) {
            float od = __shfl_xor(bd, off, 64);
            int   oi = __shfl_xor(bi, off, 64);
            if (od < bd || (od == bd && oi < bi)) { bd = od; bi = oi; }
        }

        if (lane == 0) {
            int o = b * GG + g;
            out[o]               = (float)bi;   // src_idx
            out[BB * GG + o]     = (float)g;    // tgt_idx
            out[2 * BB * GG + o] = bd;          // costs
        }
    }
}

extern "C" void kernel_launch(void* const* d_in, const int* in_sizes, int n_in,
                              void* d_out, int out_size, void* d_ws, size_t ws_size,
                              hipStream_t stream) {
    const float* pred = (const float*)d_in[0];
    const float* gt   = (const float*)d_in[1];
    const int*   lm   = (const int*)d_in[2];
    float* out = (float*)d_out;
    u16* labels = (u16*)d_ws;   // [B][P] u16, written before read, no init needed

    k_label<<<dim3(BB * PP / 256), dim3(256), 0, stream>>>(pred, lm, labels);
    k_match<<<dim3(BB * BPB), dim3(NTHR2), 0, stream>>>(pred, gt, labels, out);
}

// Round 7
// 14.147 us; speedup vs baseline: 1.1081x; 1.1081x over previous
//
#include <hip/hip_runtime.h>
#include <math.h>

#define BB 4
#define PP 16384
#define GG 512
#define HH 512
#define WW 512
#define GPB 16           // g's per block in kernel 2 (one wave per g) — R4 best config
#define BPB 32           // blocks per batch = GG/GPB
#define NTHR2 1024       // 16 waves
#define CAPL 128         // LDS bucket capacity (mean 32; P(>128) ~ 1e-40)

typedef unsigned short u16;
typedef __attribute__((ext_vector_type(8))) unsigned short u16x8;

__device__ __forceinline__ float distf(float px, float py, float gx, float gy) {
#pragma clang fp contract(off)
    float dx = px - gx;
    float dy = py - gy;
    float a = dx * dx;
    float c = dy * dy;
    return sqrtf(a + c);   // matches XLA: separate mul/add/sqrt, no FMA contraction
}

// Kernel 1: each point labeled exactly once (the only random-gather pass).
// Pure u16 writes to labels[] -> no init, no atomics, no workspace counts.
__global__ void k_label(const float* __restrict__ pred, const int* __restrict__ lm,
                        u16* __restrict__ labels) {
    int t = blockIdx.x * blockDim.x + threadIdx.x;   // [0, B*P) exactly
    int b = t >> 14;                                  // t / PP
    float2 c = ((const float2*)pred)[t];
    int x = min(max((int)rintf(c.x), 0), WW - 1);     // round half-to-even = jnp.round
    int y = min(max((int)rintf(c.y), 0), HH - 1);
    labels[t] = (u16)lm[((b << 9) + y) * WW + x];     // b*HH*WW + y*WW + x
}

// Kernel 2: one block per (batch, 16-g range). Coalesced 16B scan of the
// block's u16 labels slice -> LDS index buckets -> one wave per g resolves.
__global__ void __launch_bounds__(NTHR2) k_match(const float* __restrict__ pred,
                                                 const float* __restrict__ gt,
                                                 const u16* __restrict__ labels,
                                                 float* __restrict__ out) {
    __shared__ int cnt[GPB];
    __shared__ int bidx[GPB][CAPL];

    const int b     = blockIdx.x / BPB;
    const int gbase = (blockIdx.x % BPB) * GPB;
    const int tid   = threadIdx.x;

    if (tid < GPB) cnt[tid] = 0;
    __syncthreads();

    const float2* predb = (const float2*)(pred + (size_t)b * PP * 2);
    const u16*    labb  = labels + (size_t)b * PP;

    // ---- Phase A: coalesced u16x8 label scan, bucket indices for our 16 g's
    const u16x8* lab8 = (const u16x8*)labb;
    #pragma unroll
    for (int i = tid; i < PP / 8; i += NTHR2) {       // 2 iterations
        u16x8 lv = lab8[i];
        int p0 = i * 8;
        #pragma unroll
        for (int j = 0; j < 8; ++j) {
            int lg = (int)lv[j] - 1 - gbase;
            if ((unsigned)lg < GPB) {
                int s = atomicAdd(&cnt[lg], 1);       // LDS atomic, block-local
                if (s < CAPL) bidx[lg][s] = p0 + j;
            }
        }
    }
    __syncthreads();

    // ---- Phase B: wave w resolves g = gbase + w
    const int w    = tid >> 6;
    const int lane = tid & 63;
    const int g    = gbase + w;
    const float gx = gt[(size_t)(b * GG + g) * 2 + 0];
    const float gy = gt[(size_t)(b * GG + g) * 2 + 1];
    const int n = cnt[w];

    float bd = INFINITY;
    int   bi = 0x7fffffff;

    if (n == 0) {
        // empty mask: argmin over ALL points (reference fallback); ~never taken
        for (int p = lane; p < PP; p += 64) {
            float2 c = predb[p];
            float d = distf(c.x, c.y, gx, gy);
            if (d < bd || (d == bd && p < bi)) { bd = d; bi = p; }
        }
    } else if (n <= CAPL) {
        for (int e = lane; e < n; e += 64) {          // 1 iteration typically
            int p = bidx[w][e];
            float2 c = predb[p];
            float d = distf(c.x, c.y, gx, gy);
            if (d < bd || (d == bd && p < bi)) { bd = d; bi = p; }
        }
    } else {
        // bucket overflow (~impossible): exact coalesced re-filter
        for (int p = lane; p < PP; p += 64) {
            if ((int)labb[p] == g + 1) {
                float2 c = predb[p];
                float d = distf(c.x, c.y, gx, gy);
                if (d < bd || (d == bd && p < bi)) { bd = d; bi = p; }
            }
        }
    }

    // wave butterfly reduce: (min d, then min original index) — order-invariant
    for (int off = 32; off > 0; off >>= 1) {
        float od = __shfl_xor(bd, off, 64);
        int   oi = __shfl_xor(bi, off, 64);
        if (od < bd || (od == bd && oi < bi)) { bd = od; bi = oi; }
    }

    if (lane == 0) {
        int o = b * GG + g;
        out[o]               = (float)bi;   // src_idx
        out[BB * GG + o]     = (float)g;    // tgt_idx
        out[2 * BB * GG + o] = bd;          // costs
    }
}

extern "C" void kernel_launch(void* const* d_in, const int* in_sizes, int n_in,
                              void* d_out, int out_size, void* d_ws, size_t ws_size,
                              hipStream_t stream) {
    const float* pred = (const float*)d_in[0];
    const float* gt   = (const float*)d_in[1];
    const int*   lm   = (const int*)d_in[2];
    float* out = (float*)d_out;
    u16* labels = (u16*)d_ws;   // [B][P] u16, written before read, no init needed

    k_label<<<dim3(BB * PP / 256), dim3(256), 0, stream>>>(pred, lm, labels);
    k_match<<<dim3(BB * BPB), dim3(NTHR2), 0, stream>>>(pred, gt, labels, out);
}